// Round 22
// baseline (343.278 us; speedup 1.0000x reference)
//
#include <hip/hip_runtime.h>
#include <math.h>

#define LL 8192
#define CC 96
#define DINc 96
#define NN 16
#define RR 6
#define KK 8
#define Dd 16
#define Hh 16
#define Ww 32
#define NCH 32
#define CHL 256   // LL / NCH (scanf chunking)
#define LOG2E 1.44269504088896340736f

__device__ __forceinline__ float ex2_(float x) { return __builtin_amdgcn_exp2f(x); }

__constant__ int Pc_[4][3] = {{0,1,2},{1,2,0},{2,0,1},{2,1,0}};

__device__ __forceinline__ float silu_(float x){ return x / (1.f + __expf(-x)); }

// ---------------- K1: LN1 tiled -> xn channel-major; ALSO does weight transposes ----------------
__global__ void k_ln1(const float* __restrict__ inp, const float* __restrict__ w,
                      const float* __restrict__ b, float* __restrict__ xn_cm,
                      const float* __restrict__ inpj, const float* __restrict__ xpw,
                      const float* __restrict__ w1, const float* __restrict__ w2,
                      const float* __restrict__ opw,
                      float* __restrict__ ipT, float* __restrict__ xpT,
                      float* __restrict__ wT1, float* __restrict__ wT2,
                      float* __restrict__ opT) {
    __shared__ float tile[16][97];
    __shared__ float smean[16], srstd[16];
    int l0 = blockIdx.x * 16;
    int tid = threadIdx.x;
    // fused weight transposes (independent work, spread across blocks)
    {
        int idx = blockIdx.x * 256 + tid;
        if (idx < 82944) {   // wT1: [ic][tap][oc=32]
            int oc = idx & 31; int tap = (idx >> 5) % 27; int ic = idx / (32 * 27);
            wT1[idx] = w1[(oc * 96 + ic) * 27 + tap];
        }
        if (idx < 82944) {   // wT2: [ic][tap][oc=96]
            int oc = idx % 96; int tap = (idx / 96) % 27; int ic = idx / (96 * 27);
            wT2[idx] = w2[(oc * 32 + ic) * 27 + tap];
        }
        if (idx < 18432) {   // ipT: [c][e=192]
            int e = idx % 192; int c = idx / 192;
            ipT[idx] = inpj[e * 96 + c];
        }
        if (idx < 29184) {   // xpT: [k][c][e=38]
            int e = idx % 38; int c = (idx / 38) % 96; int k = idx / (38 * 96);
            xpT[idx] = xpw[(k * 38 + e) * 96 + c];
        }
        if (idx < 9216) {    // opT: [e][c]
            int c = idx % 96; int e = idx / 96;
            opT[idx] = opw[c * 96 + e];
        }
    }
    #pragma unroll
    for (int r = 0; r < 6; ++r) {
        int e = r * 256 + tid;
        int lo = e / 96, c = e % 96;
        tile[lo][c] = inp[(long)(l0 + lo) * 96 + c];
    }
    __syncthreads();
    {
        int lo = tid >> 4, g = tid & 15;
        float ps = 0.f;
        #pragma unroll
        for (int j = 0; j < 6; ++j) ps += tile[lo][g * 6 + j];
        #pragma unroll
        for (int o = 1; o < 16; o <<= 1) ps += __shfl_xor(ps, o, 16);
        float m = ps * (1.f / 96.f);
        float pv = 0.f;
        #pragma unroll
        for (int j = 0; j < 6; ++j) { float dd = tile[lo][g * 6 + j] - m; pv += dd * dd; }
        #pragma unroll
        for (int o = 1; o < 16; o <<= 1) pv += __shfl_xor(pv, o, 16);
        if (g == 0) { smean[lo] = m; srstd[lo] = rsqrtf(pv * (1.f / 96.f) + 1e-6f); }
    }
    __syncthreads();
    #pragma unroll
    for (int r = 0; r < 6; ++r) {
        int e = r * 256 + tid;
        int c = e >> 4, lo = e & 15;
        xn_cm[(long)c * LL + l0 + lo] = (tile[lo][c] - smean[lo]) * srstd[lo] * w[c] + b[c];
    }
}

// ---------------- K2: in_proj; x -> channel-major, z -> ROW-major ----------------
__global__ void k_inproj(const float* __restrict__ xn_cm, const float* __restrict__ ipT,
                         float* __restrict__ xcm, float* __restrict__ z_rm) {
    int bx = blockIdx.x;
    int eb = bx >> 5;
    int l  = ((bx & 31) << 8) + threadIdx.x;
    int e0 = eb << 3;
    float a[8];
    #pragma unroll
    for (int j = 0; j < 8; ++j) a[j] = 0.f;
    const float* wp = ipT + e0;
    for (int c = 0; c < CC; ++c) {
        float x = xn_cm[c * LL + l];
        const float4* wv = (const float4*)(wp + c * 192);
        float4 wa = wv[0], wb = wv[1];
        a[0] += x * wa.x; a[1] += x * wa.y; a[2] += x * wa.z; a[3] += x * wa.w;
        a[4] += x * wb.x; a[5] += x * wb.y; a[6] += x * wb.z; a[7] += x * wb.w;
    }
    if (e0 < DINc) {
        float* dst = xcm + (long)e0 * LL;
        #pragma unroll
        for (int j = 0; j < 8; ++j) dst[(long)j * LL + l] = a[j];
    } else {
        float* dst = z_rm + (long)l * DINc + (e0 - DINc);
        #pragma unroll
        for (int j = 0; j < 8; ++j) dst[j] = a[j];
    }
}

// ---------------- K3: depthwise conv3d + SiLU; writes xs[0] AND xs[4] (reversed) ----------------
__global__ void k_dwconv(const float* __restrict__ xcm, const float* __restrict__ cw,
                         const float* __restrict__ cb, float* __restrict__ xs) {
    int bx = blockIdx.x;
    int c  = bx >> 3;
    int l4 = ((bx & 7) << 8) + threadIdx.x;
    int w0 = (l4 & 7) << 2;
    int h  = (l4 >> 3) & 15;
    int d  = l4 >> 7;
    int l  = (d * Hh + h) * Ww + w0;
    float wk[27];
    #pragma unroll
    for (int t = 0; t < 27; ++t) wk[t] = cw[c * 27 + t];
    float rmask[9]; int roff[9];
    #pragma unroll
    for (int kd = 0; kd < 3; ++kd) {
        int dd = d + kd - 1;
        bool vd = (unsigned)dd < Dd; int dc = vd ? dd : 0;
        #pragma unroll
        for (int kh = 0; kh < 3; ++kh) {
            int hh = h + kh - 1;
            bool vh = (unsigned)hh < Hh; int hcl = vh ? hh : 0;
            rmask[kd * 3 + kh] = (vd && vh) ? 1.f : 0.f;
            roff[kd * 3 + kh]  = (dc * Hh + hcl) * Ww + w0;
        }
    }
    float mleft  = (w0 > 0)  ? 1.f : 0.f;
    float mright = (w0 < 28) ? 1.f : 0.f;
    float a0 = cb[c], a1 = a0, a2 = a0, a3 = a0;
    const float* xp = xcm + (long)c * LL;
    #pragma unroll
    for (int r = 0; r < 9; ++r) {
        float rm = rmask[r];
        const float* xr = xp + roff[r];
        float4 xc = *(const float4*)xr;
        float v[6];
        v[0] = xr[-1] * (rm * mleft);
        v[1] = xc.x * rm; v[2] = xc.y * rm; v[3] = xc.z * rm; v[4] = xc.w * rm;
        v[5] = xr[4] * (rm * mright);
        #pragma unroll
        for (int t = 0; t < 3; ++t) {
            float wv = wk[r * 3 + t];
            a0 += v[t + 0] * wv;
            a1 += v[t + 1] * wv;
            a2 += v[t + 2] * wv;
            a3 += v[t + 3] * wv;
        }
    }
    float s0 = silu_(a0), s1 = silu_(a1), s2 = silu_(a2), s3 = silu_(a3);
    *(float4*)(xs + (long)c * LL + l) = make_float4(s0, s1, s2, s3);
    *(float4*)(xs + ((long)(4 * DINc) + c) * LL + (LL - 4 - l)) = make_float4(s3, s2, s1, s0);
}

// ---------------- K4a: xs[1..3] via LDS transpose; also writes xs[k+4] reversed ----------------
__global__ void k_permA(float* __restrict__ xs) {
    __shared__ float lv[8192 + 256 + 16];
    int bx = blockIdx.x;
    int k = bx / 96 + 1;
    int c = bx % 96;
    const float* src = xs + (long)c * LL;
    float* dst  = xs + ((long)k * DINc + c) * LL;
    float* dst4 = xs + ((long)(k + 4) * DINc + c) * LL;
    int tid = threadIdx.x;
    for (int i = tid; i < LL; i += 256)
        lv[i + (i >> 5) + (i >> 9)] = src[i];
    __syncthreads();
    int p0 = Pc_[k][0], p1 = Pc_[k][1], p2 = Pc_[k][2];
    const int sp[3] = {Dd, Hh, Ww};
    int pd1 = sp[p1], pd2 = sp[p2];
    for (int i = tid; i < LL; i += 256) {
        int i2 = i % pd2;
        int t  = i / pd2;
        int i1 = t % pd1;
        int i0 = t / pd1;
        int coord[3];
        coord[p0] = i0; coord[p1] = i1; coord[p2] = i2;
        int o = (coord[0] * Hh + coord[1]) * Ww + coord[2];
        float v = lv[o + (o >> 5) + (o >> 9)];
        dst[i] = v;
        dst4[LL - 1 - i] = v;
    }
}

// ---------------- K5: x_dbl, 4-way e-split (10/10/10/8) ----------------
// grid 1024: bx = k*128 + lblk*4 + eh
__global__ void k_xdbl(const float* __restrict__ xs, const float* __restrict__ xpT,
                       float* __restrict__ dtr, float* __restrict__ Bb, float* __restrict__ Cb) {
    int bx = blockIdx.x;
    int k = bx >> 7;                        // uniform
    int rest = bx & 127;
    int eh = rest & 3;
    int lblk = rest >> 2;
    int l = (lblk << 8) + threadIdx.x;
    int e0 = eh * 10;
    int ne = (eh == 3) ? 8 : 10;            // block-uniform
    float acc[10];
    #pragma unroll
    for (int e = 0; e < 10; ++e) acc[e] = 0.f;
    const float* xb = xs + (long)k * DINc * LL + l;
    const float* wb = xpT + k * DINc * 38 + e0;
    for (int c = 0; c < DINc; ++c) {
        float x = xb[(long)c * LL];
        const float* wr = wb + c * 38;
        for (int e = 0; e < ne; ++e) acc[e] += x * wr[e];
    }
    int lq = l >> 2, q = l & 3;
    for (int e = 0; e < ne; ++e) {
        int ge = e0 + e;
        if (ge < RR)
            dtr[((long)k * LL + l) * 6 + ge] = acc[e];
        else if (ge < RR + NN)
            Bb[(((long)k * 2048 + lq) * 16 + (ge - RR)) * 4 + q] = acc[e];
        else
            Cb[(((long)k * 2048 + lq) * 16 + (ge - RR - NN)) * 4 + q] = acc[e];
    }
}

// ---------------- softplus ----------------
__device__ __forceinline__ float softplus_(float x) {
    return (x > 20.f) ? x : __logf(1.f + __expf(x));
}

// ---------------- K7 fused scan; exp2 pre-scaled A ----------------
__global__ __launch_bounds__(512)
void k_scanf(float* __restrict__ xs_ys, const float* __restrict__ dtr,
             const float* __restrict__ Bb, const float* __restrict__ Cb,
             const float* __restrict__ A_logs, const float* __restrict__ dt_w,
             const float* __restrict__ dt_b, const float* __restrict__ Ds) {
    __shared__ __align__(16) float sdt[LL + (LL >> 7) * 4];
    __shared__ float sAp[16][33];
    __shared__ float sBc[16][33];
    __shared__ float shs[16][33];
    int bx = blockIdx.x;
    int grp = (bx & 7) * DINc + (bx >> 3);
    int k = grp / DINc;
    int tid = threadIdx.x;
    int n = tid & 15;
    int chunk = tid >> 4;
    {
        float w0 = dt_w[grp * RR + 0], w1 = dt_w[grp * RR + 1], w2 = dt_w[grp * RR + 2];
        float w3 = dt_w[grp * RR + 3], w4 = dt_w[grp * RR + 4], w5 = dt_w[grp * RR + 5];
        float dtb = dt_b[grp];
        const float* drb = dtr + (long)k * LL * 6;
        for (int i = tid; i < LL; i += 512) {
            const float2* dp = (const float2*)(drb + (long)i * 6);
            float2 d0 = dp[0], d1 = dp[1], d2 = dp[2];
            float dtl = dtb + d0.x * w0 + d0.y * w1 + d1.x * w2 + d1.y * w3 + d2.x * w4 + d2.y * w5;
            sdt[i + ((i >> 7) << 2)] = softplus_(dtl);
        }
    }
    __syncthreads();
    float A2 = -__expf(A_logs[grp * NN + n]) * LOG2E;
    const float4* sdt4 = (const float4*)sdt;
    int dbase = chunk * 66;
    const float4* u4 = (const float4*)(xs_ys + (long)grp * LL + chunk * CHL);
    const float4* B4 = (const float4*)Bb + ((long)k * 2048 + chunk * (CHL / 4)) * 16 + n;
    const float4* C4 = (const float4*)Cb + ((long)k * 2048 + chunk * (CHL / 4)) * 16 + n;
    {
        float hc = 0.f, dsum = 0.f;
        #pragma unroll 4
        for (int q = 0; q < CHL / 4; ++q) {
            float4 dt = sdt4[dbase + q + (q >> 5)];
            float4 uu = u4[q];
            float4 Bv = B4[q * 16];
            dsum += (dt.x + dt.y) + (dt.z + dt.w);
            hc = ex2_(dt.x * A2) * hc + (dt.x * uu.x) * Bv.x;
            hc = ex2_(dt.y * A2) * hc + (dt.y * uu.y) * Bv.y;
            hc = ex2_(dt.z * A2) * hc + (dt.z * uu.z) * Bv.z;
            hc = ex2_(dt.w * A2) * hc + (dt.w * uu.w) * Bv.w;
        }
        sAp[n][chunk] = ex2_(A2 * dsum);
        sBc[n][chunk] = hc;
    }
    __syncthreads();
    if (tid < 16) {
        float h = 0.f;
        for (int c = 0; c < NCH; ++c) {
            shs[tid][c] = h;
            h = sAp[tid][c] * h + sBc[tid][c];
        }
    }
    __syncthreads();
    float Dv = Ds[grp];
    float* urow = xs_ys + (long)grp * LL + chunk * CHL;
    float hc = shs[n][chunk];
    int qsel = n >> 2, csel = n & 3;
    bool b0 = (n & 1), b1 = ((n >> 1) & 1), b2 = ((n >> 2) & 1), b3 = (n >> 3);
    for (int base = 0; base < CHL; base += 16) {
        float u_lane = 0.f;
        float p[16];
        #pragma unroll
        for (int q = 0; q < 4; ++q) {
            int qq = (base >> 2) + q;
            float4 dt = sdt4[dbase + qq + (qq >> 5)];
            float4 uu = *(const float4*)(urow + base + q * 4);
            float4 Bv = B4[qq * 16];
            float4 Cv = C4[qq * 16];
            if (q == qsel)
                u_lane = (csel == 0) ? uu.x : (csel == 1) ? uu.y : (csel == 2) ? uu.z : uu.w;
            hc = ex2_(dt.x * A2) * hc + (dt.x * uu.x) * Bv.x;  p[q*4+0] = hc * Cv.x;
            hc = ex2_(dt.y * A2) * hc + (dt.y * uu.y) * Bv.y;  p[q*4+1] = hc * Cv.y;
            hc = ex2_(dt.z * A2) * hc + (dt.z * uu.z) * Bv.z;  p[q*4+2] = hc * Cv.z;
            hc = ex2_(dt.w * A2) * hc + (dt.w * uu.w) * Bv.w;  p[q*4+3] = hc * Cv.w;
        }
        float q8[8];
        #pragma unroll
        for (int m = 0; m < 8; ++m) {
            float sel = b0 ? p[2*m] : p[2*m+1];
            float r = __shfl_xor(sel, 1, 16);
            q8[m] = (b0 ? p[2*m+1] : p[2*m]) + r;
        }
        float r4[4];
        #pragma unroll
        for (int m = 0; m < 4; ++m) {
            float sel = b1 ? q8[2*m] : q8[2*m+1];
            float r = __shfl_xor(sel, 2, 16);
            r4[m] = (b1 ? q8[2*m+1] : q8[2*m]) + r;
        }
        float t2r[2];
        #pragma unroll
        for (int m = 0; m < 2; ++m) {
            float sel = b2 ? r4[2*m] : r4[2*m+1];
            float r = __shfl_xor(sel, 4, 16);
            t2r[m] = (b2 ? r4[2*m+1] : r4[2*m]) + r;
        }
        float sel = b3 ? t2r[0] : t2r[1];
        float r = __shfl_xor(sel, 8, 16);
        float yv = (b3 ? t2r[1] : t2r[0]) + r;
        urow[base + n] = yv + Dv * u_lane;
    }
}

// ---------------- K8..K11 fused: combine + LN + silu(z) + out_proj + skip1 + LN2 -> y2 ----------------
__global__ void k_combproj(const float* __restrict__ ys, const float* __restrict__ z_rm,
                           const float* __restrict__ w, const float* __restrict__ b,
                           const float* __restrict__ opT, const float* __restrict__ inp,
                           const float* __restrict__ skip1, float* __restrict__ xafter,
                           const float* __restrict__ w2, const float* __restrict__ b2,
                           float* __restrict__ y2) {
    __shared__ float sy[4][96];
    int wave = threadIdx.x >> 6;
    int lane = threadIdx.x & 63;
    int l = blockIdx.x * 4 + wave;
    int d = l >> 9, h = (l >> 5) & 15, wd = l & 31;
    int lps[4];
    lps[0] = l;
    lps[1] = (h * 32 + wd) * 16 + d;
    lps[2] = (wd * 16 + d) * 16 + h;
    lps[3] = (wd * 16 + h) * 16 + d;
    int c0 = lane, c1 = 64 + lane;
    float a0 = 0.f, a1 = 0.f;
    #pragma unroll
    for (int i = 0; i < 4; ++i) {
        a0 += ys[((long)(i * 96) + c0) * LL + lps[i]];
        a0 += ys[((long)((4 + i) * 96) + c0) * LL + (LL - 1 - lps[i])];
    }
    if (lane < 32) {
        #pragma unroll
        for (int i = 0; i < 4; ++i) {
            a1 += ys[((long)(i * 96) + c1) * LL + lps[i]];
            a1 += ys[((long)((4 + i) * 96) + c1) * LL + (LL - 1 - lps[i])];
        }
    }
    float s = a0 + a1;
    #pragma unroll
    for (int o = 1; o < 64; o <<= 1) s += __shfl_xor(s, o, 64);
    float m = s * (1.f / 96.f);
    float d0 = a0 - m;
    float d1 = (lane < 32) ? (a1 - m) : 0.f;
    float ss = d0 * d0 + d1 * d1;
    #pragma unroll
    for (int o = 1; o < 64; o <<= 1) ss += __shfl_xor(ss, o, 64);
    float r = rsqrtf(ss * (1.f / 96.f) + 1e-5f);
    float zz = z_rm[(long)l * 96 + c0];
    sy[wave][c0] = (d0 * r * w[c0] + b[c0]) * silu_(zz);
    if (lane < 32) {
        float z1 = z_rm[(long)l * 96 + c1];
        sy[wave][c1] = (d1 * r * w[c1] + b[c1]) * silu_(z1);
    }
    __syncthreads();
    int c1g = (lane < 32) ? c1 : 0;
    float o0 = 0.f, o1 = 0.f;
    #pragma unroll 4
    for (int e = 0; e < 96; ++e) {
        float ye = sy[wave][e];
        o0 += ye * opT[e * 96 + c0];
        o1 += ye * opT[e * 96 + c1g];
    }
    float xa0 = inp[(long)l * 96 + c0] * skip1[c0] + o0;
    float xa1 = 0.f;
    xafter[(long)l * 96 + c0] = xa0;
    if (lane < 32) {
        xa1 = inp[(long)l * 96 + c1] * skip1[c1] + o1;
        xafter[(long)l * 96 + c1] = xa1;
    }
    float s2 = xa0 + ((lane < 32) ? xa1 : 0.f);
    #pragma unroll
    for (int o = 1; o < 64; o <<= 1) s2 += __shfl_xor(s2, o, 64);
    float m2 = s2 * (1.f / 96.f);
    float e0v = xa0 - m2;
    float e1v = (lane < 32) ? (xa1 - m2) : 0.f;
    float ss2 = e0v * e0v + e1v * e1v;
    #pragma unroll
    for (int o = 1; o < 64; o <<= 1) ss2 += __shfl_xor(ss2, o, 64);
    float r2 = rsqrtf(ss2 * (1.f / 96.f) + 1e-5f);
    __syncthreads();
    sy[wave][c0] = e0v * r2 * w2[c0] + b2[c0];
    if (lane < 32)
        sy[wave][c1] = e1v * r2 * w2[c1] + b2[c1];
    __syncthreads();
    int l0 = blockIdx.x * 4;
    #pragma unroll
    for (int rr = 0; rr < 2; ++rr) {
        int e = rr * 256 + threadIdx.x;
        if (e < 384) {
            int c = e >> 2, j = e & 3;
            y2[(long)c * LL + l0 + j] = sy[j][c];
        }
    }
}

// ---------------- K12: conv3d 96->32, 4 oc x 4 pos, 16-way ic-split (grid 1024) ----------------
__global__ void k_conv1(const float* __restrict__ y2, const float* __restrict__ wT,
                        float* __restrict__ part) {
    int bx = blockIdx.x;
    int g  = bx >> 3;
    int ocg = g & 7;
    int isp = g >> 3;
    int l4 = ((bx & 7) << 8) + threadIdx.x;
    int w0 = (l4 & 7) << 2;
    int h  = (l4 >> 3) & 15;
    int d  = l4 >> 7;
    int l  = (d * Hh + h) * Ww + w0;
    float rmask[9]; int roff[9];
    #pragma unroll
    for (int kd = 0; kd < 3; ++kd) {
        int dd = d + kd - 1;
        bool vd = (unsigned)dd < Dd; int dc = vd ? dd : 0;
        #pragma unroll
        for (int kh = 0; kh < 3; ++kh) {
            int hh = h + kh - 1;
            bool vh = (unsigned)hh < Hh; int hcl = vh ? hh : 0;
            rmask[kd * 3 + kh] = (vd && vh) ? 1.f : 0.f;
            roff[kd * 3 + kh]  = (dc * Hh + hcl) * Ww + w0;
        }
    }
    float mleft  = (w0 > 0)  ? 1.f : 0.f;
    float mright = (w0 < 28) ? 1.f : 0.f;
    float acc[16];
    #pragma unroll
    for (int j = 0; j < 16; ++j) acc[j] = 0.f;
    for (int ic = isp * 6; ic < isp * 6 + 6; ++ic) {
        const float* xp = y2 + (long)ic * LL;
        const float* wb = wT + ic * 864 + ocg * 4;
        #pragma unroll
        for (int r = 0; r < 9; ++r) {
            float rm = rmask[r];
            const float* xr = xp + roff[r];
            float4 xc = *(const float4*)xr;
            float v[6];
            v[0] = xr[-1] * (rm * mleft);
            v[1] = xc.x * rm; v[2] = xc.y * rm; v[3] = xc.z * rm; v[4] = xc.w * rm;
            v[5] = xr[4] * (rm * mright);
            #pragma unroll
            for (int t = 0; t < 3; ++t) {
                float4 wa = *(const float4*)(wb + (r * 3 + t) * 32);
                #pragma unroll
                for (int p = 0; p < 4; ++p) {
                    float x = v[t + p];
                    acc[0  + p] += x * wa.x;  acc[4  + p] += x * wa.y;
                    acc[8  + p] += x * wa.z;  acc[12 + p] += x * wa.w;
                }
            }
        }
    }
    float* pp = part + ((long)(isp * 32 + ocg * 4)) * LL + l;
    #pragma unroll
    for (int oc = 0; oc < 4; ++oc)
        *(float4*)(pp + (long)oc * LL) = make_float4(acc[oc*4+0], acc[oc*4+1], acc[oc*4+2], acc[oc*4+3]);
}

// ---------------- K12b: t1 = GELU(sum 16 partials + bias); float4 ----------------
__global__ void k_gelusum(const float* __restrict__ part, const float* __restrict__ b1,
                          float* __restrict__ t1) {
    int idx = blockIdx.x * blockDim.x + threadIdx.x;
    if (idx >= 32 * (LL / 4)) return;
    int lq = idx & (LL / 4 - 1);
    int oc = idx >> 11;
    float bv = b1[oc];
    float4 s = make_float4(bv, bv, bv, bv);
    #pragma unroll
    for (int isp = 0; isp < 16; ++isp) {
        float4 v = *(const float4*)(part + ((long)(isp * 32 + oc)) * LL + lq * 4);
        s.x += v.x; s.y += v.y; s.z += v.z; s.w += v.w;
    }
    float4 o;
    o.x = 0.5f * s.x * (1.f + erff(s.x * 0.70710678118654752f));
    o.y = 0.5f * s.y * (1.f + erff(s.y * 0.70710678118654752f));
    o.z = 0.5f * s.z * (1.f + erff(s.z * 0.70710678118654752f));
    o.w = 0.5f * s.w * (1.f + erff(s.w * 0.70710678118654752f));
    *(float4*)(t1 + (long)oc * LL + lq * 4) = o;
}

// ---------------- K13: conv3d 32->96, 4 oc x 4 pos, 8-way ic-split (grid 1536) ----------------
__global__ void k_conv2(const float* __restrict__ t1, const float* __restrict__ wT,
                        float* __restrict__ part) {
    int bx = blockIdx.x;
    int g  = bx >> 3;
    int ocg = g % 24;
    int isp = g / 24;
    int l4 = ((bx & 7) << 8) + threadIdx.x;
    int w0 = (l4 & 7) << 2;
    int h  = (l4 >> 3) & 15;
    int d  = l4 >> 7;
    int l  = (d * Hh + h) * Ww + w0;
    float rmask[9]; int roff[9];
    #pragma unroll
    for (int kd = 0; kd < 3; ++kd) {
        int dd = d + kd - 1;
        bool vd = (unsigned)dd < Dd; int dc = vd ? dd : 0;
        #pragma unroll
        for (int kh = 0; kh < 3; ++kh) {
            int hh = h + kh - 1;
            bool vh = (unsigned)hh < Hh; int hcl = vh ? hh : 0;
            rmask[kd * 3 + kh] = (vd && vh) ? 1.f : 0.f;
            roff[kd * 3 + kh]  = (dc * Hh + hcl) * Ww + w0;
        }
    }
    float mleft  = (w0 > 0)  ? 1.f : 0.f;
    float mright = (w0 < 28) ? 1.f : 0.f;
    float acc[16];
    #pragma unroll
    for (int j = 0; j < 16; ++j) acc[j] = 0.f;
    for (int ic = isp * 4; ic < isp * 4 + 4; ++ic) {
        const float* xp = t1 + (long)ic * LL;
        const float* wb = wT + ic * 2592 + ocg * 4;
        #pragma unroll
        for (int r = 0; r < 9; ++r) {
            float rm = rmask[r];
            const float* xr = xp + roff[r];
            float4 xc = *(const float4*)xr;
            float v[6];
            v[0] = xr[-1] * (rm * mleft);
            v[1] = xc.x * rm; v[2] = xc.y * rm; v[3] = xc.z * rm; v[4] = xc.w * rm;
            v[5] = xr[4] * (rm * mright);
            #pragma unroll
            for (int t = 0; t < 3; ++t) {
                float4 wa = *(const float4*)(wb + (r * 3 + t) * 96);
                #pragma unroll
                for (int p = 0; p < 4; ++p) {
                    float x = v[t + p];
                    acc[0  + p] += x * wa.x;  acc[4  + p] += x * wa.y;
                    acc[8  + p] += x * wa.z;  acc[12 + p] += x * wa.w;
                }
            }
        }
    }
    float* pp = part + ((long)(isp * 96 + ocg * 4)) * LL + l;
    #pragma unroll
    for (int oc = 0; oc < 4; ++oc)
        *(float4*)(pp + (long)oc * LL) = make_float4(acc[oc*4+0], acc[oc*4+1], acc[oc*4+2], acc[oc*4+3]);
}

// ---------------- K13b: t2 = sum 8 partials + bias; float4 + per-block mean partial ----------------
__global__ void k_conv2sum(const float* __restrict__ part, const float* __restrict__ b2,
                           float* __restrict__ t2, float* __restrict__ pmean) {
    __shared__ float sm[256];
    int idx = blockIdx.x * 256 + threadIdx.x;
    int lq = idx & (LL / 4 - 1);
    int oc = idx >> 11;
    float bv = b2[oc];
    float4 s = make_float4(bv, bv, bv, bv);
    #pragma unroll
    for (int isp = 0; isp < 8; ++isp) {
        float4 v = *(const float4*)(part + ((long)(isp * 96 + oc)) * LL + lq * 4);
        s.x += v.x; s.y += v.y; s.z += v.z; s.w += v.w;
    }
    *(float4*)(t2 + (long)oc * LL + lq * 4) = s;
    sm[threadIdx.x] = (s.x + s.y) + (s.z + s.w);
    __syncthreads();
    for (int o = 128; o > 0; o >>= 1) {
        if (threadIdx.x < o) sm[threadIdx.x] += sm[threadIdx.x + o];
        __syncthreads();
    }
    if (threadIdx.x == 0) pmean[blockIdx.x] = sm[0];
}

// ---------------- K14b: channel-attention MLP (folds pmean partials) ----------------
__global__ void k_mlp(const float* __restrict__ pmean, const float* __restrict__ w1,
                      const float* __restrict__ b1, const float* __restrict__ w2,
                      const float* __restrict__ b2, float* __restrict__ v2) {
    __shared__ float mb[96];
    __shared__ float v[48];
    int t = threadIdx.x;
    if (t < 96) {
        float s = 0.f;
        #pragma unroll
        for (int j = 0; j < 8; ++j) s += pmean[t * 8 + j];
        mb[t] = s * (1.f / LL);
    }
    __syncthreads();
    if (t < 48) {
        float s = b1[t];
        for (int c = 0; c < 96; ++c) s += mb[c] * w1[t * 96 + c];
        v[t] = fmaxf(s, 0.f);
    }
    __syncthreads();
    if (t < 96) {
        float s = b2[t];
        for (int j = 0; j < 48; ++j) s += v[j] * w2[t * 48 + j];
        v2[t] = 1.f / (1.f + __expf(-s));
    }
}

// ---------------- K15: final residual; 512-block LDS tile ----------------
__global__ void k_final(const float* __restrict__ xafter, const float* __restrict__ skip2,
                        const float* __restrict__ t2, const float* __restrict__ v2,
                        float* __restrict__ out) {
    __shared__ float tile[96][17];
    __shared__ float sk2[96], sv2[96];
    int l0 = blockIdx.x * 16;
    int tid = threadIdx.x;
    if (tid < 96) { sk2[tid] = skip2[tid]; sv2[tid] = v2[tid]; }
    #pragma unroll
    for (int r = 0; r < 6; ++r) {
        int e = r * 256 + tid;
        int c = e >> 4, lo = e & 15;
        tile[c][lo] = t2[(long)c * LL + l0 + lo];
    }
    __syncthreads();
    #pragma unroll
    for (int r = 0; r < 6; ++r) {
        int e = r * 256 + tid;
        int lo = e / 96, c = e % 96;
        long gi = (long)(l0 + lo) * 96 + c;
        out[gi] = xafter[gi] * sk2[c] + tile[c][lo] * sv2[c];
    }
}

// ---------------- workspace layout (float offsets) ----------------
static const size_t OFF_XS     = 0;          // 8*96*8192
static const size_t OFF_Z      = 6291456;    // 786432 (z row-major)
static const size_t OFF_XCM    = 7077888;    // 786432
static const size_t OFF_XN     = 7864320;    // 786432 (xn_cm)
static const size_t OFF_DTRAW  = 8650752;    // 393216 ([k][l][6])
static const size_t OFF_BB     = 9043968;    // 1048576 ([k][l/4][n][4])
static const size_t OFF_CB     = 10092544;   // 1048576
static const size_t OFF_XAFTER = 11141120;   // 786432
static const size_t OFF_Y2     = 11927552;   // 786432
static const size_t OFF_T1     = 12713984;   // 262144
static const size_t OFF_T2     = 12976128;   // 786432
static const size_t OFF_MV     = 13762560;   // 1024 (pmean[768] + v2[96])
static const size_t OFF_WT1    = 13763584;   // 82944
static const size_t OFF_WT2    = 13846528;   // 82944
static const size_t OFF_IPT    = 13929472;   // 18432
static const size_t OFF_XPT    = 13947904;   // 29184
static const size_t OFF_OPT    = 13977088;   // 9216

extern "C" void kernel_launch(void* const* d_in, const int* in_sizes, int n_in,
                              void* d_out, int out_size, void* d_ws, size_t ws_size,
                              hipStream_t stream) {
    const float* inp    = (const float*)d_in[0];
    const float* ln1_w  = (const float*)d_in[2];
    const float* ln1_b  = (const float*)d_in[3];
    const float* skip1  = (const float*)d_in[4];
    const float* skip2  = (const float*)d_in[5];
    const float* ln2_w  = (const float*)d_in[6];
    const float* ln2_b  = (const float*)d_in[7];
    const float* inpj   = (const float*)d_in[8];
    const float* conv_w = (const float*)d_in[9];
    const float* conv_b = (const float*)d_in[10];
    const float* xpw    = (const float*)d_in[11];
    const float* dt_w   = (const float*)d_in[12];
    const float* dt_b   = (const float*)d_in[13];
    const float* A_logs = (const float*)d_in[14];
    const float* Ds     = (const float*)d_in[15];
    const float* onw    = (const float*)d_in[16];
    const float* onb    = (const float*)d_in[17];
    const float* opw    = (const float*)d_in[18];
    const float* cab_w1 = (const float*)d_in[19];
    const float* cab_b1 = (const float*)d_in[20];
    const float* cab_w2 = (const float*)d_in[21];
    const float* cab_b2 = (const float*)d_in[22];
    const float* ca_w1  = (const float*)d_in[23];
    const float* ca_b1  = (const float*)d_in[24];
    const float* ca_w2  = (const float*)d_in[25];
    const float* ca_b2  = (const float*)d_in[26];

    float* ws = (float*)d_ws;
    float* xs     = ws + OFF_XS;
    float* zbuf   = ws + OFF_Z;
    float* xcm    = ws + OFF_XCM;
    float* xn     = ws + OFF_XN;
    float* dtr    = ws + OFF_DTRAW;
    float* Bb     = ws + OFF_BB;
    float* Cb     = ws + OFF_CB;
    float* xafter = ws + OFF_XAFTER;
    float* y2     = ws + OFF_Y2;
    float* t1     = ws + OFF_T1;
    float* t2     = ws + OFF_T2;
    float* mv     = ws + OFF_MV;          // pmean[768], v2 at +768
    float* wT1    = ws + OFF_WT1;
    float* wT2    = ws + OFF_WT2;
    float* ipT    = ws + OFF_IPT;
    float* xpT    = ws + OFF_XPT;
    float* opT    = ws + OFF_OPT;
    float* part1  = xs;                  // xs dead after combproj
    float* part2  = xs;

    float* out = (float*)d_out;
    #define GRID(n) dim3((unsigned)(((n) + 255) / 256)), dim3(256)

    hipLaunchKernelGGL(k_ln1,     dim3(512), dim3(256),       0, stream, inp, ln1_w, ln1_b, xn,
                       inpj, xpw, cab_w1, cab_w2, opw, ipT, xpT, wT1, wT2, opT);
    hipLaunchKernelGGL(k_inproj,  dim3(768), dim3(256),       0, stream, xn, ipT, xcm, zbuf);
    hipLaunchKernelGGL(k_dwconv,  dim3(768), dim3(256),       0, stream, xcm, conv_w, conv_b, xs);
    hipLaunchKernelGGL(k_permA,   dim3(288), dim3(256),       0, stream, xs);
    hipLaunchKernelGGL(k_xdbl,    dim3(1024), dim3(256),      0, stream, xs, xpT, dtr, Bb, Cb);
    hipLaunchKernelGGL(k_scanf,   dim3(KK * DINc), dim3(512), 0, stream, xs, dtr, Bb, Cb, A_logs, dt_w, dt_b, Ds);
    hipLaunchKernelGGL(k_combproj,dim3(LL / 4), dim3(256),    0, stream, xs, zbuf, onw, onb, opT, inp, skip1, xafter, ln2_w, ln2_b, y2);
    hipLaunchKernelGGL(k_conv1,   dim3(1024), dim3(256),      0, stream, y2, wT1, part1);
    hipLaunchKernelGGL(k_gelusum, GRID(32 * (LL / 4)),        0, stream, part1, cab_b1, t1);
    hipLaunchKernelGGL(k_conv2,   dim3(1536), dim3(256),      0, stream, t1, wT2, part2);
    hipLaunchKernelGGL(k_conv2sum,dim3(768), dim3(256),       0, stream, part2, cab_b2, t2, mv);
    hipLaunchKernelGGL(k_mlp,     dim3(1), dim3(128),         0, stream, mv, ca_w1, ca_b1, ca_w2, ca_b2, mv + 768);
    hipLaunchKernelGGL(k_final,   dim3(512), dim3(256),       0, stream, xafter, skip2, t2, mv + 768, out);
    #undef GRID
}

// Round 23
// 262.728 us; speedup vs baseline: 1.3066x; 1.3066x over previous
//
#include <hip/hip_runtime.h>
#include <math.h>

#define LL 8192
#define CC 96
#define DINc 96
#define NN 16
#define RR 6
#define KK 8
#define Dd 16
#define Hh 16
#define Ww 32
#define NCH 32
#define CHL 256   // LL / NCH (scanf chunking)
#define LOG2E 1.44269504088896340736f

__device__ __forceinline__ float ex2_(float x) { return __builtin_amdgcn_exp2f(x); }

__constant__ int Pc_[4][3] = {{0,1,2},{1,2,0},{2,0,1},{2,1,0}};

__device__ __forceinline__ float silu_(float x){ return x / (1.f + __expf(-x)); }

// ---------------- K1: LN1 tiled -> xn channel-major; ALSO does weight transposes ----------------
__global__ void k_ln1(const float* __restrict__ inp, const float* __restrict__ w,
                      const float* __restrict__ b, float* __restrict__ xn_cm,
                      const float* __restrict__ inpj, const float* __restrict__ xpw,
                      const float* __restrict__ w1, const float* __restrict__ w2,
                      const float* __restrict__ opw,
                      float* __restrict__ ipT, float* __restrict__ xpT,
                      float* __restrict__ wT1, float* __restrict__ wT2,
                      float* __restrict__ opT) {
    __shared__ float tile[16][97];
    __shared__ float smean[16], srstd[16];
    int l0 = blockIdx.x * 16;
    int tid = threadIdx.x;
    {
        int idx = blockIdx.x * 256 + tid;
        if (idx < 82944) {   // wT1: [ic][tap][oc=32]
            int oc = idx & 31; int tap = (idx >> 5) % 27; int ic = idx / (32 * 27);
            wT1[idx] = w1[(oc * 96 + ic) * 27 + tap];
        }
        if (idx < 82944) {   // wT2: [ic][tap][oc=96]
            int oc = idx % 96; int tap = (idx / 96) % 27; int ic = idx / (96 * 27);
            wT2[idx] = w2[(oc * 32 + ic) * 27 + tap];
        }
        if (idx < 18432) {   // ipT: [c][e=192]
            int e = idx % 192; int c = idx / 192;
            ipT[idx] = inpj[e * 96 + c];
        }
        if (idx < 29184) {   // xpT: [k][c][e=38]
            int e = idx % 38; int c = (idx / 38) % 96; int k = idx / (38 * 96);
            xpT[idx] = xpw[(k * 38 + e) * 96 + c];
        }
        if (idx < 9216) {    // opT: [e][c]
            int c = idx % 96; int e = idx / 96;
            opT[idx] = opw[c * 96 + e];
        }
    }
    #pragma unroll
    for (int r = 0; r < 6; ++r) {
        int e = r * 256 + tid;
        int lo = e / 96, c = e % 96;
        tile[lo][c] = inp[(long)(l0 + lo) * 96 + c];
    }
    __syncthreads();
    {
        int lo = tid >> 4, g = tid & 15;
        float ps = 0.f;
        #pragma unroll
        for (int j = 0; j < 6; ++j) ps += tile[lo][g * 6 + j];
        #pragma unroll
        for (int o = 1; o < 16; o <<= 1) ps += __shfl_xor(ps, o, 16);
        float m = ps * (1.f / 96.f);
        float pv = 0.f;
        #pragma unroll
        for (int j = 0; j < 6; ++j) { float dd = tile[lo][g * 6 + j] - m; pv += dd * dd; }
        #pragma unroll
        for (int o = 1; o < 16; o <<= 1) pv += __shfl_xor(pv, o, 16);
        if (g == 0) { smean[lo] = m; srstd[lo] = rsqrtf(pv * (1.f / 96.f) + 1e-6f); }
    }
    __syncthreads();
    #pragma unroll
    for (int r = 0; r < 6; ++r) {
        int e = r * 256 + tid;
        int c = e >> 4, lo = e & 15;
        xn_cm[(long)c * LL + l0 + lo] = (tile[lo][c] - smean[lo]) * srstd[lo] * w[c] + b[c];
    }
}

// ---------------- K2: in_proj; x -> channel-major, z -> ROW-major ----------------
__global__ void k_inproj(const float* __restrict__ xn_cm, const float* __restrict__ ipT,
                         float* __restrict__ xcm, float* __restrict__ z_rm) {
    int bx = blockIdx.x;
    int eb = bx >> 5;
    int l  = ((bx & 31) << 8) + threadIdx.x;
    int e0 = eb << 3;
    float a[8];
    #pragma unroll
    for (int j = 0; j < 8; ++j) a[j] = 0.f;
    const float* wp = ipT + e0;
    for (int c = 0; c < CC; ++c) {
        float x = xn_cm[c * LL + l];
        const float4* wv = (const float4*)(wp + c * 192);
        float4 wa = wv[0], wb = wv[1];
        a[0] += x * wa.x; a[1] += x * wa.y; a[2] += x * wa.z; a[3] += x * wa.w;
        a[4] += x * wb.x; a[5] += x * wb.y; a[6] += x * wb.z; a[7] += x * wb.w;
    }
    if (e0 < DINc) {
        float* dst = xcm + (long)e0 * LL;
        #pragma unroll
        for (int j = 0; j < 8; ++j) dst[(long)j * LL + l] = a[j];
    } else {
        float* dst = z_rm + (long)l * DINc + (e0 - DINc);
        #pragma unroll
        for (int j = 0; j < 8; ++j) dst[j] = a[j];
    }
}

// ---------------- K3: depthwise conv3d + SiLU; writes xs[0] AND xs[4] (reversed) ----------------
__global__ void k_dwconv(const float* __restrict__ xcm, const float* __restrict__ cw,
                         const float* __restrict__ cb, float* __restrict__ xs) {
    int bx = blockIdx.x;
    int c  = bx >> 3;
    int l4 = ((bx & 7) << 8) + threadIdx.x;
    int w0 = (l4 & 7) << 2;
    int h  = (l4 >> 3) & 15;
    int d  = l4 >> 7;
    int l  = (d * Hh + h) * Ww + w0;
    float wk[27];
    #pragma unroll
    for (int t = 0; t < 27; ++t) wk[t] = cw[c * 27 + t];
    float rmask[9]; int roff[9];
    #pragma unroll
    for (int kd = 0; kd < 3; ++kd) {
        int dd = d + kd - 1;
        bool vd = (unsigned)dd < Dd; int dc = vd ? dd : 0;
        #pragma unroll
        for (int kh = 0; kh < 3; ++kh) {
            int hh = h + kh - 1;
            bool vh = (unsigned)hh < Hh; int hcl = vh ? hh : 0;
            rmask[kd * 3 + kh] = (vd && vh) ? 1.f : 0.f;
            roff[kd * 3 + kh]  = (dc * Hh + hcl) * Ww + w0;
        }
    }
    float mleft  = (w0 > 0)  ? 1.f : 0.f;
    float mright = (w0 < 28) ? 1.f : 0.f;
    float a0 = cb[c], a1 = a0, a2 = a0, a3 = a0;
    const float* xp = xcm + (long)c * LL;
    #pragma unroll
    for (int r = 0; r < 9; ++r) {
        float rm = rmask[r];
        const float* xr = xp + roff[r];
        float4 xc = *(const float4*)xr;
        float v[6];
        v[0] = xr[-1] * (rm * mleft);
        v[1] = xc.x * rm; v[2] = xc.y * rm; v[3] = xc.z * rm; v[4] = xc.w * rm;
        v[5] = xr[4] * (rm * mright);
        #pragma unroll
        for (int t = 0; t < 3; ++t) {
            float wv = wk[r * 3 + t];
            a0 += v[t + 0] * wv;
            a1 += v[t + 1] * wv;
            a2 += v[t + 2] * wv;
            a3 += v[t + 3] * wv;
        }
    }
    float s0 = silu_(a0), s1 = silu_(a1), s2 = silu_(a2), s3 = silu_(a3);
    *(float4*)(xs + (long)c * LL + l) = make_float4(s0, s1, s2, s3);
    *(float4*)(xs + ((long)(4 * DINc) + c) * LL + (LL - 4 - l)) = make_float4(s3, s2, s1, s0);
}

// ---------------- K4a: xs[1..3] via LDS transpose; also writes xs[k+4] reversed ----------------
__global__ void k_permA(float* __restrict__ xs) {
    __shared__ float lv[8192 + 256 + 16];
    int bx = blockIdx.x;
    int k = bx / 96 + 1;
    int c = bx % 96;
    const float* src = xs + (long)c * LL;
    float* dst  = xs + ((long)k * DINc + c) * LL;
    float* dst4 = xs + ((long)(k + 4) * DINc + c) * LL;
    int tid = threadIdx.x;
    for (int i = tid; i < LL; i += 256)
        lv[i + (i >> 5) + (i >> 9)] = src[i];
    __syncthreads();
    int p0 = Pc_[k][0], p1 = Pc_[k][1], p2 = Pc_[k][2];
    const int sp[3] = {Dd, Hh, Ww};
    int pd1 = sp[p1], pd2 = sp[p2];
    for (int i = tid; i < LL; i += 256) {
        int i2 = i % pd2;
        int t  = i / pd2;
        int i1 = t % pd1;
        int i0 = t / pd1;
        int coord[3];
        coord[p0] = i0; coord[p1] = i1; coord[p2] = i2;
        int o = (coord[0] * Hh + coord[1]) * Ww + coord[2];
        float v = lv[o + (o >> 5) + (o >> 9)];
        dst[i] = v;
        dst4[LL - 1 - i] = v;
    }
}

// ---------------- K5: x_dbl, 2-way e-split (19 acc each, compile-time bounds) ----------------
// grid 512: bx = k*64 + lblk*2 + eh
__global__ void k_xdbl(const float* __restrict__ xs, const float* __restrict__ xpT,
                       float* __restrict__ dtr, float* __restrict__ Bb, float* __restrict__ Cb) {
    int bx = blockIdx.x;
    int k = bx >> 6;
    int rest = bx & 63;
    int eh = rest & 1;
    int lblk = rest >> 1;
    int l = (lblk << 8) + threadIdx.x;
    int e0 = eh * 19;
    float acc[19];
    #pragma unroll
    for (int e = 0; e < 19; ++e) acc[e] = 0.f;
    const float* xb = xs + (long)k * DINc * LL + l;
    const float* wb = xpT + k * DINc * 38 + e0;
    for (int c = 0; c < DINc; ++c) {
        float x = xb[(long)c * LL];
        const float* wr = wb + c * 38;
        #pragma unroll
        for (int e = 0; e < 19; ++e) acc[e] += x * wr[e];
    }
    int lq = l >> 2, q = l & 3;
    #pragma unroll
    for (int e = 0; e < 19; ++e) {
        int ge = e0 + e;
        if (ge < RR)
            dtr[((long)k * LL + l) * 6 + ge] = acc[e];
        else if (ge < RR + NN)
            Bb[(((long)k * 2048 + lq) * 16 + (ge - RR)) * 4 + q] = acc[e];
        else
            Cb[(((long)k * 2048 + lq) * 16 + (ge - RR - NN)) * 4 + q] = acc[e];
    }
}

// ---------------- softplus ----------------
__device__ __forceinline__ float softplus_(float x) {
    return (x > 20.f) ? x : __logf(1.f + __expf(x));
}

// ---------------- K7 fused scan; exp2 pre-scaled A ----------------
__global__ __launch_bounds__(512)
void k_scanf(float* __restrict__ xs_ys, const float* __restrict__ dtr,
             const float* __restrict__ Bb, const float* __restrict__ Cb,
             const float* __restrict__ A_logs, const float* __restrict__ dt_w,
             const float* __restrict__ dt_b, const float* __restrict__ Ds) {
    __shared__ __align__(16) float sdt[LL + (LL >> 7) * 4];
    __shared__ float sAp[16][33];
    __shared__ float sBc[16][33];
    __shared__ float shs[16][33];
    int bx = blockIdx.x;
    int grp = (bx & 7) * DINc + (bx >> 3);
    int k = grp / DINc;
    int tid = threadIdx.x;
    int n = tid & 15;
    int chunk = tid >> 4;
    {
        float w0 = dt_w[grp * RR + 0], w1 = dt_w[grp * RR + 1], w2 = dt_w[grp * RR + 2];
        float w3 = dt_w[grp * RR + 3], w4 = dt_w[grp * RR + 4], w5 = dt_w[grp * RR + 5];
        float dtb = dt_b[grp];
        const float* drb = dtr + (long)k * LL * 6;
        for (int i = tid; i < LL; i += 512) {
            const float2* dp = (const float2*)(drb + (long)i * 6);
            float2 d0 = dp[0], d1 = dp[1], d2 = dp[2];
            float dtl = dtb + d0.x * w0 + d0.y * w1 + d1.x * w2 + d1.y * w3 + d2.x * w4 + d2.y * w5;
            sdt[i + ((i >> 7) << 2)] = softplus_(dtl);
        }
    }
    __syncthreads();
    float A2 = -__expf(A_logs[grp * NN + n]) * LOG2E;
    const float4* sdt4 = (const float4*)sdt;
    int dbase = chunk * 66;
    const float4* u4 = (const float4*)(xs_ys + (long)grp * LL + chunk * CHL);
    const float4* B4 = (const float4*)Bb + ((long)k * 2048 + chunk * (CHL / 4)) * 16 + n;
    const float4* C4 = (const float4*)Cb + ((long)k * 2048 + chunk * (CHL / 4)) * 16 + n;
    {
        float hc = 0.f, dsum = 0.f;
        #pragma unroll 4
        for (int q = 0; q < CHL / 4; ++q) {
            float4 dt = sdt4[dbase + q + (q >> 5)];
            float4 uu = u4[q];
            float4 Bv = B4[q * 16];
            dsum += (dt.x + dt.y) + (dt.z + dt.w);
            hc = ex2_(dt.x * A2) * hc + (dt.x * uu.x) * Bv.x;
            hc = ex2_(dt.y * A2) * hc + (dt.y * uu.y) * Bv.y;
            hc = ex2_(dt.z * A2) * hc + (dt.z * uu.z) * Bv.z;
            hc = ex2_(dt.w * A2) * hc + (dt.w * uu.w) * Bv.w;
        }
        sAp[n][chunk] = ex2_(A2 * dsum);
        sBc[n][chunk] = hc;
    }
    __syncthreads();
    if (tid < 16) {
        float h = 0.f;
        for (int c = 0; c < NCH; ++c) {
            shs[tid][c] = h;
            h = sAp[tid][c] * h + sBc[tid][c];
        }
    }
    __syncthreads();
    float Dv = Ds[grp];
    float* urow = xs_ys + (long)grp * LL + chunk * CHL;
    float hc = shs[n][chunk];
    int qsel = n >> 2, csel = n & 3;
    bool b0 = (n & 1), b1 = ((n >> 1) & 1), b2 = ((n >> 2) & 1), b3 = (n >> 3);
    for (int base = 0; base < CHL; base += 16) {
        float u_lane = 0.f;
        float p[16];
        #pragma unroll
        for (int q = 0; q < 4; ++q) {
            int qq = (base >> 2) + q;
            float4 dt = sdt4[dbase + qq + (qq >> 5)];
            float4 uu = *(const float4*)(urow + base + q * 4);
            float4 Bv = B4[qq * 16];
            float4 Cv = C4[qq * 16];
            if (q == qsel)
                u_lane = (csel == 0) ? uu.x : (csel == 1) ? uu.y : (csel == 2) ? uu.z : uu.w;
            hc = ex2_(dt.x * A2) * hc + (dt.x * uu.x) * Bv.x;  p[q*4+0] = hc * Cv.x;
            hc = ex2_(dt.y * A2) * hc + (dt.y * uu.y) * Bv.y;  p[q*4+1] = hc * Cv.y;
            hc = ex2_(dt.z * A2) * hc + (dt.z * uu.z) * Bv.z;  p[q*4+2] = hc * Cv.z;
            hc = ex2_(dt.w * A2) * hc + (dt.w * uu.w) * Bv.w;  p[q*4+3] = hc * Cv.w;
        }
        float q8[8];
        #pragma unroll
        for (int m = 0; m < 8; ++m) {
            float sel = b0 ? p[2*m] : p[2*m+1];
            float r = __shfl_xor(sel, 1, 16);
            q8[m] = (b0 ? p[2*m+1] : p[2*m]) + r;
        }
        float r4[4];
        #pragma unroll
        for (int m = 0; m < 4; ++m) {
            float sel = b1 ? q8[2*m] : q8[2*m+1];
            float r = __shfl_xor(sel, 2, 16);
            r4[m] = (b1 ? q8[2*m+1] : q8[2*m]) + r;
        }
        float t2r[2];
        #pragma unroll
        for (int m = 0; m < 2; ++m) {
            float sel = b2 ? r4[2*m] : r4[2*m+1];
            float r = __shfl_xor(sel, 4, 16);
            t2r[m] = (b2 ? r4[2*m+1] : r4[2*m]) + r;
        }
        float sel = b3 ? t2r[0] : t2r[1];
        float r = __shfl_xor(sel, 8, 16);
        float yv = (b3 ? t2r[1] : t2r[0]) + r;
        urow[base + n] = yv + Dv * u_lane;
    }
}

// ---------------- K8..K11 fused: combine + LN + silu(z) + out_proj + skip1 + LN2 -> y2 ----------------
__global__ void k_combproj(const float* __restrict__ ys, const float* __restrict__ z_rm,
                           const float* __restrict__ w, const float* __restrict__ b,
                           const float* __restrict__ opT, const float* __restrict__ inp,
                           const float* __restrict__ skip1, float* __restrict__ xafter,
                           const float* __restrict__ w2, const float* __restrict__ b2,
                           float* __restrict__ y2) {
    __shared__ float sy[4][96];
    int wave = threadIdx.x >> 6;
    int lane = threadIdx.x & 63;
    int l = blockIdx.x * 4 + wave;
    int d = l >> 9, h = (l >> 5) & 15, wd = l & 31;
    int lps[4];
    lps[0] = l;
    lps[1] = (h * 32 + wd) * 16 + d;
    lps[2] = (wd * 16 + d) * 16 + h;
    lps[3] = (wd * 16 + h) * 16 + d;
    int c0 = lane, c1 = 64 + lane;
    float a0 = 0.f, a1 = 0.f;
    #pragma unroll
    for (int i = 0; i < 4; ++i) {
        a0 += ys[((long)(i * 96) + c0) * LL + lps[i]];
        a0 += ys[((long)((4 + i) * 96) + c0) * LL + (LL - 1 - lps[i])];
    }
    if (lane < 32) {
        #pragma unroll
        for (int i = 0; i < 4; ++i) {
            a1 += ys[((long)(i * 96) + c1) * LL + lps[i]];
            a1 += ys[((long)((4 + i) * 96) + c1) * LL + (LL - 1 - lps[i])];
        }
    }
    float s = a0 + a1;
    #pragma unroll
    for (int o = 1; o < 64; o <<= 1) s += __shfl_xor(s, o, 64);
    float m = s * (1.f / 96.f);
    float d0 = a0 - m;
    float d1 = (lane < 32) ? (a1 - m) : 0.f;
    float ss = d0 * d0 + d1 * d1;
    #pragma unroll
    for (int o = 1; o < 64; o <<= 1) ss += __shfl_xor(ss, o, 64);
    float r = rsqrtf(ss * (1.f / 96.f) + 1e-5f);
    float zz = z_rm[(long)l * 96 + c0];
    sy[wave][c0] = (d0 * r * w[c0] + b[c0]) * silu_(zz);
    if (lane < 32) {
        float z1 = z_rm[(long)l * 96 + c1];
        sy[wave][c1] = (d1 * r * w[c1] + b[c1]) * silu_(z1);
    }
    __syncthreads();
    int c1g = (lane < 32) ? c1 : 0;
    float o0 = 0.f, o1 = 0.f;
    #pragma unroll 4
    for (int e = 0; e < 96; ++e) {
        float ye = sy[wave][e];
        o0 += ye * opT[e * 96 + c0];
        o1 += ye * opT[e * 96 + c1g];
    }
    float xa0 = inp[(long)l * 96 + c0] * skip1[c0] + o0;
    float xa1 = 0.f;
    xafter[(long)l * 96 + c0] = xa0;
    if (lane < 32) {
        xa1 = inp[(long)l * 96 + c1] * skip1[c1] + o1;
        xafter[(long)l * 96 + c1] = xa1;
    }
    float s2 = xa0 + ((lane < 32) ? xa1 : 0.f);
    #pragma unroll
    for (int o = 1; o < 64; o <<= 1) s2 += __shfl_xor(s2, o, 64);
    float m2 = s2 * (1.f / 96.f);
    float e0v = xa0 - m2;
    float e1v = (lane < 32) ? (xa1 - m2) : 0.f;
    float ss2 = e0v * e0v + e1v * e1v;
    #pragma unroll
    for (int o = 1; o < 64; o <<= 1) ss2 += __shfl_xor(ss2, o, 64);
    float r2 = rsqrtf(ss2 * (1.f / 96.f) + 1e-5f);
    __syncthreads();
    sy[wave][c0] = e0v * r2 * w2[c0] + b2[c0];
    if (lane < 32)
        sy[wave][c1] = e1v * r2 * w2[c1] + b2[c1];
    __syncthreads();
    int l0 = blockIdx.x * 4;
    #pragma unroll
    for (int rr = 0; rr < 2; ++rr) {
        int e = rr * 256 + threadIdx.x;
        if (e < 384) {
            int c = e >> 2, j = e & 3;
            y2[(long)c * LL + l0 + j] = sy[j][c];
        }
    }
}

// ---------------- K12: conv3d 96->32, 4 oc x 4 pos, 16-way ic-split (grid 1024) ----------------
__global__ void k_conv1(const float* __restrict__ y2, const float* __restrict__ wT,
                        float* __restrict__ part) {
    int bx = blockIdx.x;
    int g  = bx >> 3;
    int ocg = g & 7;
    int isp = g >> 3;
    int l4 = ((bx & 7) << 8) + threadIdx.x;
    int w0 = (l4 & 7) << 2;
    int h  = (l4 >> 3) & 15;
    int d  = l4 >> 7;
    int l  = (d * Hh + h) * Ww + w0;
    float rmask[9]; int roff[9];
    #pragma unroll
    for (int kd = 0; kd < 3; ++kd) {
        int dd = d + kd - 1;
        bool vd = (unsigned)dd < Dd; int dc = vd ? dd : 0;
        #pragma unroll
        for (int kh = 0; kh < 3; ++kh) {
            int hh = h + kh - 1;
            bool vh = (unsigned)hh < Hh; int hcl = vh ? hh : 0;
            rmask[kd * 3 + kh] = (vd && vh) ? 1.f : 0.f;
            roff[kd * 3 + kh]  = (dc * Hh + hcl) * Ww + w0;
        }
    }
    float mleft  = (w0 > 0)  ? 1.f : 0.f;
    float mright = (w0 < 28) ? 1.f : 0.f;
    float acc[16];
    #pragma unroll
    for (int j = 0; j < 16; ++j) acc[j] = 0.f;
    for (int ic = isp * 6; ic < isp * 6 + 6; ++ic) {
        const float* xp = y2 + (long)ic * LL;
        const float* wb = wT + ic * 864 + ocg * 4;
        #pragma unroll
        for (int r = 0; r < 9; ++r) {
            float rm = rmask[r];
            const float* xr = xp + roff[r];
            float4 xc = *(const float4*)xr;
            float v[6];
            v[0] = xr[-1] * (rm * mleft);
            v[1] = xc.x * rm; v[2] = xc.y * rm; v[3] = xc.z * rm; v[4] = xc.w * rm;
            v[5] = xr[4] * (rm * mright);
            #pragma unroll
            for (int t = 0; t < 3; ++t) {
                float4 wa = *(const float4*)(wb + (r * 3 + t) * 32);
                #pragma unroll
                for (int p = 0; p < 4; ++p) {
                    float x = v[t + p];
                    acc[0  + p] += x * wa.x;  acc[4  + p] += x * wa.y;
                    acc[8  + p] += x * wa.z;  acc[12 + p] += x * wa.w;
                }
            }
        }
    }
    float* pp = part + ((long)(isp * 32 + ocg * 4)) * LL + l;
    #pragma unroll
    for (int oc = 0; oc < 4; ++oc)
        *(float4*)(pp + (long)oc * LL) = make_float4(acc[oc*4+0], acc[oc*4+1], acc[oc*4+2], acc[oc*4+3]);
}

// ---------------- K12b: t1 = GELU(sum 16 partials + bias); float4 ----------------
__global__ void k_gelusum(const float* __restrict__ part, const float* __restrict__ b1,
                          float* __restrict__ t1) {
    int idx = blockIdx.x * blockDim.x + threadIdx.x;
    if (idx >= 32 * (LL / 4)) return;
    int lq = idx & (LL / 4 - 1);
    int oc = idx >> 11;
    float bv = b1[oc];
    float4 s = make_float4(bv, bv, bv, bv);
    #pragma unroll
    for (int isp = 0; isp < 16; ++isp) {
        float4 v = *(const float4*)(part + ((long)(isp * 32 + oc)) * LL + lq * 4);
        s.x += v.x; s.y += v.y; s.z += v.z; s.w += v.w;
    }
    float4 o;
    o.x = 0.5f * s.x * (1.f + erff(s.x * 0.70710678118654752f));
    o.y = 0.5f * s.y * (1.f + erff(s.y * 0.70710678118654752f));
    o.z = 0.5f * s.z * (1.f + erff(s.z * 0.70710678118654752f));
    o.w = 0.5f * s.w * (1.f + erff(s.w * 0.70710678118654752f));
    *(float4*)(t1 + (long)oc * LL + lq * 4) = o;
}

// ---------------- K13: conv3d 32->96, 4 oc x 4 pos, 8-way ic-split (grid 1536) ----------------
__global__ void k_conv2(const float* __restrict__ t1, const float* __restrict__ wT,
                        float* __restrict__ part) {
    int bx = blockIdx.x;
    int g  = bx >> 3;
    int ocg = g % 24;
    int isp = g / 24;
    int l4 = ((bx & 7) << 8) + threadIdx.x;
    int w0 = (l4 & 7) << 2;
    int h  = (l4 >> 3) & 15;
    int d  = l4 >> 7;
    int l  = (d * Hh + h) * Ww + w0;
    float rmask[9]; int roff[9];
    #pragma unroll
    for (int kd = 0; kd < 3; ++kd) {
        int dd = d + kd - 1;
        bool vd = (unsigned)dd < Dd; int dc = vd ? dd : 0;
        #pragma unroll
        for (int kh = 0; kh < 3; ++kh) {
            int hh = h + kh - 1;
            bool vh = (unsigned)hh < Hh; int hcl = vh ? hh : 0;
            rmask[kd * 3 + kh] = (vd && vh) ? 1.f : 0.f;
            roff[kd * 3 + kh]  = (dc * Hh + hcl) * Ww + w0;
        }
    }
    float mleft  = (w0 > 0)  ? 1.f : 0.f;
    float mright = (w0 < 28) ? 1.f : 0.f;
    float acc[16];
    #pragma unroll
    for (int j = 0; j < 16; ++j) acc[j] = 0.f;
    for (int ic = isp * 4; ic < isp * 4 + 4; ++ic) {
        const float* xp = t1 + (long)ic * LL;
        const float* wb = wT + ic * 2592 + ocg * 4;
        #pragma unroll
        for (int r = 0; r < 9; ++r) {
            float rm = rmask[r];
            const float* xr = xp + roff[r];
            float4 xc = *(const float4*)xr;
            float v[6];
            v[0] = xr[-1] * (rm * mleft);
            v[1] = xc.x * rm; v[2] = xc.y * rm; v[3] = xc.z * rm; v[4] = xc.w * rm;
            v[5] = xr[4] * (rm * mright);
            #pragma unroll
            for (int t = 0; t < 3; ++t) {
                float4 wa = *(const float4*)(wb + (r * 3 + t) * 96);
                #pragma unroll
                for (int p = 0; p < 4; ++p) {
                    float x = v[t + p];
                    acc[0  + p] += x * wa.x;  acc[4  + p] += x * wa.y;
                    acc[8  + p] += x * wa.z;  acc[12 + p] += x * wa.w;
                }
            }
        }
    }
    float* pp = part + ((long)(isp * 96 + ocg * 4)) * LL + l;
    #pragma unroll
    for (int oc = 0; oc < 4; ++oc)
        *(float4*)(pp + (long)oc * LL) = make_float4(acc[oc*4+0], acc[oc*4+1], acc[oc*4+2], acc[oc*4+3]);
}

// ---------------- K13b: t2 = sum 8 partials + bias; float4 + per-block mean partial ----------------
__global__ void k_conv2sum(const float* __restrict__ part, const float* __restrict__ b2,
                           float* __restrict__ t2, float* __restrict__ pmean) {
    __shared__ float sm[256];
    int idx = blockIdx.x * 256 + threadIdx.x;
    int lq = idx & (LL / 4 - 1);
    int oc = idx >> 11;
    float bv = b2[oc];
    float4 s = make_float4(bv, bv, bv, bv);
    #pragma unroll
    for (int isp = 0; isp < 8; ++isp) {
        float4 v = *(const float4*)(part + ((long)(isp * 96 + oc)) * LL + lq * 4);
        s.x += v.x; s.y += v.y; s.z += v.z; s.w += v.w;
    }
    *(float4*)(t2 + (long)oc * LL + lq * 4) = s;
    sm[threadIdx.x] = (s.x + s.y) + (s.z + s.w);
    __syncthreads();
    for (int o = 128; o > 0; o >>= 1) {
        if (threadIdx.x < o) sm[threadIdx.x] += sm[threadIdx.x + o];
        __syncthreads();
    }
    if (threadIdx.x == 0) pmean[blockIdx.x] = sm[0];
}

// ---------------- K14b: channel-attention MLP (folds pmean partials) ----------------
__global__ void k_mlp(const float* __restrict__ pmean, const float* __restrict__ w1,
                      const float* __restrict__ b1, const float* __restrict__ w2,
                      const float* __restrict__ b2, float* __restrict__ v2) {
    __shared__ float mb[96];
    __shared__ float v[48];
    int t = threadIdx.x;
    if (t < 96) {
        float s = 0.f;
        #pragma unroll
        for (int j = 0; j < 8; ++j) s += pmean[t * 8 + j];
        mb[t] = s * (1.f / LL);
    }
    __syncthreads();
    if (t < 48) {
        float s = b1[t];
        for (int c = 0; c < 96; ++c) s += mb[c] * w1[t * 96 + c];
        v[t] = fmaxf(s, 0.f);
    }
    __syncthreads();
    if (t < 96) {
        float s = b2[t];
        for (int j = 0; j < 48; ++j) s += v[j] * w2[t * 48 + j];
        v2[t] = 1.f / (1.f + __expf(-s));
    }
}

// ---------------- K15: final residual; 512-block LDS tile ----------------
__global__ void k_final(const float* __restrict__ xafter, const float* __restrict__ skip2,
                        const float* __restrict__ t2, const float* __restrict__ v2,
                        float* __restrict__ out) {
    __shared__ float tile[96][17];
    __shared__ float sk2[96], sv2[96];
    int l0 = blockIdx.x * 16;
    int tid = threadIdx.x;
    if (tid < 96) { sk2[tid] = skip2[tid]; sv2[tid] = v2[tid]; }
    #pragma unroll
    for (int r = 0; r < 6; ++r) {
        int e = r * 256 + tid;
        int c = e >> 4, lo = e & 15;
        tile[c][lo] = t2[(long)c * LL + l0 + lo];
    }
    __syncthreads();
    #pragma unroll
    for (int r = 0; r < 6; ++r) {
        int e = r * 256 + tid;
        int lo = e / 96, c = e % 96;
        long gi = (long)(l0 + lo) * 96 + c;
        out[gi] = xafter[gi] * sk2[c] + tile[c][lo] * sv2[c];
    }
}

// ---------------- workspace layout (float offsets) ----------------
static const size_t OFF_XS     = 0;          // 8*96*8192
static const size_t OFF_Z      = 6291456;    // 786432 (z row-major)
static const size_t OFF_XCM    = 7077888;    // 786432
static const size_t OFF_XN     = 7864320;    // 786432 (xn_cm)
static const size_t OFF_DTRAW  = 8650752;    // 393216 ([k][l][6])
static const size_t OFF_BB     = 9043968;    // 1048576 ([k][l/4][n][4])
static const size_t OFF_CB     = 10092544;   // 1048576
static const size_t OFF_XAFTER = 11141120;   // 786432
static const size_t OFF_Y2     = 11927552;   // 786432
static const size_t OFF_T1     = 12713984;   // 262144
static const size_t OFF_T2     = 12976128;   // 786432
static const size_t OFF_MV     = 13762560;   // 1024 (pmean[768] + v2[96])
static const size_t OFF_WT1    = 13763584;   // 82944
static const size_t OFF_WT2    = 13846528;   // 82944
static const size_t OFF_IPT    = 13929472;   // 18432
static const size_t OFF_XPT    = 13947904;   // 29184
static const size_t OFF_OPT    = 13977088;   // 9216

extern "C" void kernel_launch(void* const* d_in, const int* in_sizes, int n_in,
                              void* d_out, int out_size, void* d_ws, size_t ws_size,
                              hipStream_t stream) {
    const float* inp    = (const float*)d_in[0];
    const float* ln1_w  = (const float*)d_in[2];
    const float* ln1_b  = (const float*)d_in[3];
    const float* skip1  = (const float*)d_in[4];
    const float* skip2  = (const float*)d_in[5];
    const float* ln2_w  = (const float*)d_in[6];
    const float* ln2_b  = (const float*)d_in[7];
    const float* inpj   = (const float*)d_in[8];
    const float* conv_w = (const float*)d_in[9];
    const float* conv_b = (const float*)d_in[10];
    const float* xpw    = (const float*)d_in[11];
    const float* dt_w   = (const float*)d_in[12];
    const float* dt_b   = (const float*)d_in[13];
    const float* A_logs = (const float*)d_in[14];
    const float* Ds     = (const float*)d_in[15];
    const float* onw    = (const float*)d_in[16];
    const float* onb    = (const float*)d_in[17];
    const float* opw    = (const float*)d_in[18];
    const float* cab_w1 = (const float*)d_in[19];
    const float* cab_b1 = (const float*)d_in[20];
    const float* cab_w2 = (const float*)d_in[21];
    const float* cab_b2 = (const float*)d_in[22];
    const float* ca_w1  = (const float*)d_in[23];
    const float* ca_b1  = (const float*)d_in[24];
    const float* ca_w2  = (const float*)d_in[25];
    const float* ca_b2  = (const float*)d_in[26];

    float* ws = (float*)d_ws;
    float* xs     = ws + OFF_XS;
    float* zbuf   = ws + OFF_Z;
    float* xcm    = ws + OFF_XCM;
    float* xn     = ws + OFF_XN;
    float* dtr    = ws + OFF_DTRAW;
    float* Bb     = ws + OFF_BB;
    float* Cb     = ws + OFF_CB;
    float* xafter = ws + OFF_XAFTER;
    float* y2     = ws + OFF_Y2;
    float* t1     = ws + OFF_T1;
    float* t2     = ws + OFF_T2;
    float* mv     = ws + OFF_MV;          // pmean[768], v2 at +768
    float* wT1    = ws + OFF_WT1;
    float* wT2    = ws + OFF_WT2;
    float* ipT    = ws + OFF_IPT;
    float* xpT    = ws + OFF_XPT;
    float* opT    = ws + OFF_OPT;
    float* part1  = xs;                  // xs dead after combproj
    float* part2  = xs;

    float* out = (float*)d_out;
    #define GRID(n) dim3((unsigned)(((n) + 255) / 256)), dim3(256)

    hipLaunchKernelGGL(k_ln1,     dim3(512), dim3(256),       0, stream, inp, ln1_w, ln1_b, xn,
                       inpj, xpw, cab_w1, cab_w2, opw, ipT, xpT, wT1, wT2, opT);
    hipLaunchKernelGGL(k_inproj,  dim3(768), dim3(256),       0, stream, xn, ipT, xcm, zbuf);
    hipLaunchKernelGGL(k_dwconv,  dim3(768), dim3(256),       0, stream, xcm, conv_w, conv_b, xs);
    hipLaunchKernelGGL(k_permA,   dim3(288), dim3(256),       0, stream, xs);
    hipLaunchKernelGGL(k_xdbl,    dim3(512), dim3(256),       0, stream, xs, xpT, dtr, Bb, Cb);
    hipLaunchKernelGGL(k_scanf,   dim3(KK * DINc), dim3(512), 0, stream, xs, dtr, Bb, Cb, A_logs, dt_w, dt_b, Ds);
    hipLaunchKernelGGL(k_combproj,dim3(LL / 4), dim3(256),    0, stream, xs, zbuf, onw, onb, opT, inp, skip1, xafter, ln2_w, ln2_b, y2);
    hipLaunchKernelGGL(k_conv1,   dim3(1024), dim3(256),      0, stream, y2, wT1, part1);
    hipLaunchKernelGGL(k_gelusum, GRID(32 * (LL / 4)),        0, stream, part1, cab_b1, t1);
    hipLaunchKernelGGL(k_conv2,   dim3(1536), dim3(256),      0, stream, t1, wT2, part2);
    hipLaunchKernelGGL(k_conv2sum,dim3(768), dim3(256),       0, stream, part2, cab_b2, t2, mv);
    hipLaunchKernelGGL(k_mlp,     dim3(1), dim3(128),         0, stream, mv, ca_w1, ca_b1, ca_w2, ca_b2, mv + 768);
    hipLaunchKernelGGL(k_final,   dim3(512), dim3(256),       0, stream, xafter, skip2, t2, mv + 768, out);
    #undef GRID
}